// Round 4
// baseline (183.200 us; speedup 1.0000x reference)
//
#include <hip/hip_runtime.h>

// Involution: B=16, C=256, H=W=56, mid=64, GROUPS=16, GROUP_SIZE=16, K=3 (KK=9)
// All fp32. Output (16,256,56,56).
//
// This revision:
//  conv1: lane = OUTPUT channel. Weights become coalesced per-lane vector
//         loads (L2-hot 64 KB); x becomes wave-uniform s_load (scalar pipe).
//         -> no LDS staging, no barriers in the hot loop. One LDS transpose
//         bounce at the end keeps t in [o][px] layout.
//  conv2_inv: XCD-local t (quads of a pixel chunk share bid%8 with the conv1
//         writer block), 4-deep register pipeline for involution taps with
//         pre-barrier issue, launch_bounds(256,4) for VGPR headroom.

#define Cn    256
#define MID   64
#define Hn    56
#define Wn    56
#define HW    3136
#define Bn    16
#define NPIX  (Bn * HW)       // 50176
#define CHW   (Cn * HW)
#define NKK   9
#define NG    16
#define GSZ   16
#define PXT   64              // pixels per chunk (49 chunks/batch, 784 total)
#define BN_EPS 1e-5f

// async global->LDS: per-lane global src, wave-uniform LDS base + lane*size
#define GLOAD_LDS(src, dst, sz)                                                        \
  __builtin_amdgcn_global_load_lds(                                                    \
      (const __attribute__((address_space(1))) void*)(src),                            \
      (__attribute__((address_space(3))) void*)(dst), (sz), 0, 0)

// ---------------------------------------------------------------------------
// prep: w1f[c*64+o] = w1[o*256+c] * scale[o];  bias1[o] = beta[o]-mean[o]*scale[o]
// ---------------------------------------------------------------------------
__global__ __launch_bounds__(256) void prep_kernel(
    const float* __restrict__ w1,
    const float* __restrict__ gamma,
    const float* __restrict__ beta,
    const float* __restrict__ mean,
    const float* __restrict__ var,
    float* __restrict__ w1f,
    float* __restrict__ bias1) {
  int idx = blockIdx.x * 256 + threadIdx.x;
  if (idx < MID * Cn) {
    int c = idx >> 6;
    int o = idx & 63;
    float scale = gamma[o] / sqrtf(var[o] + BN_EPS);
    w1f[idx] = w1[o * Cn + c] * scale;
  } else if (idx < MID * Cn + MID) {
    int o = idx - MID * Cn;
    float scale = gamma[o] / sqrtf(var[o] + BN_EPS);
    bias1[o] = beta[o] - mean[o] * scale;
  }
}

// ---------------------------------------------------------------------------
// conv1: t[o][px] = relu(bias1[o] + sum_c x[b,c,px] * w1f[c*64+o])
// Block = 64 px (4 waves x 16-px strips), grid 784 (pc == bid, xcd = pc%8).
// Lane = output o. Per c: 1 coalesced weight load (VMEM, L2-hot) +
// wave-uniform x strip via s_load (scalar pipe) + 16 FMA. No barriers in
// the hot loop; one padded-LDS transpose at the end for coalesced t stores.
// ---------------------------------------------------------------------------
__global__ __launch_bounds__(256) void conv1_kernel(
    const float* __restrict__ x,
    const float* __restrict__ w1f,
    const float* __restrict__ bias1,
    float* __restrict__ t) {
  __shared__ float lt2[PXT][MID + 1];   // 64 x 65 fp32 = 16.6 KB (pad: no conflicts)

  const int tid  = threadIdx.x;
  const int lane = tid & 63;                                   // = output o
  const int wv   = __builtin_amdgcn_readfirstlane(tid >> 6);   // 0..3

  const int bid = blockIdx.x;          // one 64-px chunk, batch-aligned
  const int b   = bid / 49;
  const int hw0 = (bid - b * 49) * PXT + wv * 16;   // wave's 16-px strip (uniform)
  const float* xs = x + (size_t)b * CHW + hw0;      // uniform base

  float acc[16];
#pragma unroll
  for (int p = 0; p < 16; ++p) acc[p] = 0.0f;

  const float* wp = w1f + lane;

  for (int c = 0; c < Cn; c += 4) {
    const float w0 = wp[(c + 0) << 6];              // per-lane, coalesced
    const float w1 = wp[(c + 1) << 6];
    const float w2 = wp[(c + 2) << 6];
    const float w3 = wp[(c + 3) << 6];
    const float* x0 = xs + (size_t)(c + 0) * HW;    // uniform -> s_load
    const float* x1 = xs + (size_t)(c + 1) * HW;
    const float* x2 = xs + (size_t)(c + 2) * HW;
    const float* x3 = xs + (size_t)(c + 3) * HW;
#pragma unroll
    for (int p = 0; p < 16; ++p) acc[p] = fmaf(x0[p], w0, acc[p]);
#pragma unroll
    for (int p = 0; p < 16; ++p) acc[p] = fmaf(x1[p], w1, acc[p]);
#pragma unroll
    for (int p = 0; p < 16; ++p) acc[p] = fmaf(x2[p], w2, acc[p]);
#pragma unroll
    for (int p = 0; p < 16; ++p) acc[p] = fmaf(x3[p], w3, acc[p]);
  }

  const float bias = bias1[lane];
#pragma unroll
  for (int p = 0; p < 16; ++p)
    lt2[wv * 16 + p][lane] = fmaxf(acc[p] + bias, 0.0f);
  __syncthreads();

  // transpose-out: thread -> row o = tid>>2, px quarter q = tid&3
  const int orow = tid >> 2;
  const int q    = tid & 3;
  float v[16];
#pragma unroll
  for (int j = 0; j < 16; ++j) v[j] = lt2[q * 16 + j][orow];
  float* tp = t + (size_t)orow * NPIX + bid * PXT + q * 16;
#pragma unroll
  for (int j = 0; j < 16; j += 4)
    *(float4*)(tp + j) = make_float4(v[j], v[j + 1], v[j + 2], v[j + 3]);
}

// ---------------------------------------------------------------------------
// conv2 + involution. Block = 64 px x ONE group-quad, grid 3136.
// bid decode: pc = (bid>>5)*8 + (bid&7), gq = (bid>>3)&3  -> all 4 quads of a
// pc share bid%8 (= conv1 writer's bid%8 = pc%8) AND sit 8 blocks apart in
// dispatch order => t tile is fetched ~once per XCD L2, hot for all quads.
// Involution taps: 4-deep register pipeline (p0..p3), first 4 channels issued
// BEFORE the staging barrier (they complete under the vmcnt drain for free).
// ---------------------------------------------------------------------------
#define LOADCH(dst, ch)                                                   \
  {                                                                       \
    const float* _xp = xcg + (size_t)(ch) * HW;                           \
    _Pragma("unroll")                                                     \
    for (int kk = 0; kk < NKK; ++kk) dst[kk] = _xp[off[kk]];              \
  }
#define CONSUME(src, ch)                                                  \
  {                                                                       \
    float s0 = wk[0] * src[0];                                            \
    float s1 = wk[1] * src[1];                                            \
    float s2 = wk[2] * src[2];                                            \
    s0 = fmaf(wk[3], src[3], s0);                                         \
    s1 = fmaf(wk[4], src[4], s1);                                         \
    s2 = fmaf(wk[5], src[5], s2);                                         \
    s0 = fmaf(wk[6], src[6], s0);                                         \
    s1 = fmaf(wk[7], src[7], s1);                                         \
    s2 = fmaf(wk[8], src[8], s2);                                         \
    ob[(size_t)(ch) * HW] = s0 + s1 + s2;                                 \
  }

__global__ __launch_bounds__(256, 4) void conv2_inv_kernel(
    const float* __restrict__ x,
    const float* __restrict__ t,
    const float* __restrict__ w2,
    const float* __restrict__ b2,
    float* __restrict__ out) {
  __shared__ __align__(16) float lt[MID][PXT];          // 16 KB

  const int tid = threadIdx.x;
  const int px  = tid & 63;
  const int wv  = __builtin_amdgcn_readfirstlane(tid >> 6);   // 0..3

  const int bid = blockIdx.x;
  const int pc  = ((bid >> 5) << 3) + (bid & 7);   // pixel chunk 0..783
  const int gq  = (bid >> 3) & 3;                  // group quad 0..3
  const int g   = (gq << 2) + wv;                  // wave's group (uniform)

  const int px0 = pc * PXT;
  const int b   = px0 / HW;
  const int hw0 = px0 - b * HW;

  const int rsub = px >> 4;
  const int csub = (px & 15) << 2;

  // ---- issue t-tile staging (async) ----
#pragma unroll
  for (int j = 0; j < 4; ++j) {
    const int r0 = (wv << 4) + (j << 2);
    GLOAD_LDS(t + (size_t)(r0 + rsub) * NPIX + px0 + csub, &lt[r0][0], 16);
  }

  // ---- tap geometry (pure VALU, overlaps staging) ----
  const int hw = hw0 + px;
  const int h  = hw / Wn;
  const int w  = hw - h * Wn;

  int off[NKK];
  unsigned vmask = 0;
#pragma unroll
  for (int kk = 0; kk < NKK; ++kk) {
    const int di  = kk / 3 - 1;
    const int dj  = kk % 3 - 1;
    const int h2  = h + di;
    const int w2v = w + dj;
    const bool valid = ((unsigned)h2 < (unsigned)Hn) && ((unsigned)w2v < (unsigned)Wn);
    off[kk] = valid ? (h2 * Wn + w2v) : hw;
    vmask |= (valid ? 1u : 0u) << kk;
  }

  // ---- pre-issue first 4 channels' taps (complete under the barrier drain) ----
  const float* xcg = x + (size_t)b * CHW + (size_t)(g * GSZ) * HW;
  float p0[NKK], p1[NKK], p2[NKK], p3[NKK];
  LOADCH(p0, 0)
  LOADCH(p1, 1)
  LOADCH(p2, 2)
  LOADCH(p3, 3)

  __syncthreads();

  // ---- conv2: per-pixel kernel weights for group g, in registers ----
  float a[NKK];
#pragma unroll
  for (int kk = 0; kk < NKK; ++kk) a[kk] = b2[g * NKK + kk];   // uniform s_load

  const float* wg = w2 + (size_t)g * (NKK * MID);              // uniform base
#pragma unroll 4
  for (int o4 = 0; o4 < MID; o4 += 4) {
    const float t0 = lt[o4 + 0][px];
    const float t1 = lt[o4 + 1][px];
    const float t2 = lt[o4 + 2][px];
    const float t3 = lt[o4 + 3][px];
#pragma unroll
    for (int kk = 0; kk < NKK; ++kk) {
      const float4 w4 = *(const float4*)(wg + (kk << 6) + o4); // scalar pipe
      a[kk] = fmaf(t3, w4.w, fmaf(t2, w4.z, fmaf(t1, w4.y, fmaf(t0, w4.x, a[kk]))));
    }
  }

  float wk[NKK];
#pragma unroll
  for (int kk = 0; kk < NKK; ++kk)
    wk[kk] = ((vmask >> kk) & 1u) ? a[kk] : 0.0f;

  // ---- involution: 4-deep software pipeline over 16 channels ----
  float* ob = out + (size_t)b * CHW + (size_t)(g * GSZ) * HW + hw;

  CONSUME(p0, 0)  LOADCH(p0, 4)
  CONSUME(p1, 1)  LOADCH(p1, 5)
  CONSUME(p2, 2)  LOADCH(p2, 6)
  CONSUME(p3, 3)  LOADCH(p3, 7)
  CONSUME(p0, 4)  LOADCH(p0, 8)
  CONSUME(p1, 5)  LOADCH(p1, 9)
  CONSUME(p2, 6)  LOADCH(p2, 10)
  CONSUME(p3, 7)  LOADCH(p3, 11)
  CONSUME(p0, 8)  LOADCH(p0, 12)
  CONSUME(p1, 9)  LOADCH(p1, 13)
  CONSUME(p2, 10) LOADCH(p2, 14)
  CONSUME(p3, 11) LOADCH(p3, 15)
  CONSUME(p0, 12)
  CONSUME(p1, 13)
  CONSUME(p2, 14)
  CONSUME(p3, 15)
}

// ---------------------------------------------------------------------------
extern "C" void kernel_launch(void* const* d_in, const int* in_sizes, int n_in,
                              void* d_out, int out_size, void* d_ws, size_t ws_size,
                              hipStream_t stream) {
  const float* x     = (const float*)d_in[0];
  const float* w1    = (const float*)d_in[1];
  const float* gamma = (const float*)d_in[2];
  const float* beta  = (const float*)d_in[3];
  const float* mean  = (const float*)d_in[4];
  const float* var   = (const float*)d_in[5];
  const float* w2    = (const float*)d_in[6];
  const float* b2    = (const float*)d_in[7];
  float* out = (float*)d_out;

  // workspace: t (64 x 50176 fp32 = 12.85 MB) | w1f (64 KB) | bias1 (256 B)
  char* ws = (char*)d_ws;
  float* t     = (float*)ws;
  float* w1f   = (float*)(ws + (size_t)MID * NPIX * 4);
  float* bias1 = (float*)(ws + (size_t)MID * NPIX * 4 + (size_t)MID * Cn * 4);

  prep_kernel<<<(MID * Cn + MID + 255) / 256, 256, 0, stream>>>(
      w1, gamma, beta, mean, var, w1f, bias1);
  conv1_kernel<<<NPIX / PXT, 256, 0, stream>>>(x, w1f, bias1, t);
  conv2_inv_kernel<<<NPIX / PXT * 4, 256, 0, stream>>>(x, t, w2, b2, out);
}

// Round 5
// 161.110 us; speedup vs baseline: 1.1371x; 1.1371x over previous
//
#include <hip/hip_runtime.h>

// Involution: B=16, C=256, H=W=56, mid=64, GROUPS=16, GROUP_SIZE=16, K=3 (KK=9)
// All fp32. Output (16,256,56,56).
//
// conv1: round-3 structure (LDS x-staging + scalar-pipe weights) upgraded to
//        TRIPLE-buffered staging with counted s_waitcnt vmcnt(1) + raw
//        s_barrier -> prefetch stays in flight across barriers (T3/T4).
// conv2_inv: round-4 version kept (XCD-local t remap + 4-deep tap pipeline).

#define Cn    256
#define MID   64
#define Hn    56
#define Wn    56
#define HW    3136
#define Bn    16
#define NPIX  (Bn * HW)       // 50176
#define CHW   (Cn * HW)
#define NKK   9
#define NG    16
#define GSZ   16
#define PXT   64              // pixels per chunk (49 chunks/batch, 784 total)
#define BN_EPS 1e-5f

// async global->LDS: per-lane global src, wave-uniform LDS base + lane*size
#define GLOAD_LDS(src, dst, sz)                                                        \
  __builtin_amdgcn_global_load_lds(                                                    \
      (const __attribute__((address_space(1))) void*)(src),                            \
      (__attribute__((address_space(3))) void*)(dst), (sz), 0, 0)

// ---------------------------------------------------------------------------
// prep: w1f[c*64+o] = w1[o*256+c] * scale[o];  bias1[o] = beta[o]-mean[o]*scale[o]
// ---------------------------------------------------------------------------
__global__ __launch_bounds__(256) void prep_kernel(
    const float* __restrict__ w1,
    const float* __restrict__ gamma,
    const float* __restrict__ beta,
    const float* __restrict__ mean,
    const float* __restrict__ var,
    float* __restrict__ w1f,
    float* __restrict__ bias1) {
  int idx = blockIdx.x * 256 + threadIdx.x;
  if (idx < MID * Cn) {
    int c = idx >> 6;
    int o = idx & 63;
    float scale = gamma[o] / sqrtf(var[o] + BN_EPS);
    w1f[idx] = w1[o * Cn + c] * scale;
  } else if (idx < MID * Cn + MID) {
    int o = idx - MID * Cn;
    float scale = gamma[o] / sqrtf(var[o] + BN_EPS);
    bias1[o] = beta[o] - mean[o] * scale;
  }
}

// ---------------------------------------------------------------------------
// conv1: t[o][px] = relu(bias1[o] + sum_c x[b,c,px] * w1f[c*64+o])
// Block = 64 px x 32 outputs (grid 1568). Wave wv -> outputs oh*32+wv*8..+7.
//  - x: 16-channel tiles in TRIPLE-buffered LDS, one width-16 global_load_lds
//    per wave per tile, 2 tiles in flight (counted vmcnt, never drained to 0
//    in the main loop).
//  - weights: wave-uniform s_load (scalar pipe), 8 floats per channel.
// LDS = 12 KB. Per tile: 16 ds_read_b32 + 128 FMA per thread.
// ---------------------------------------------------------------------------
__global__ __launch_bounds__(256) void conv1_kernel(
    const float* __restrict__ x,
    const float* __restrict__ w1f,
    const float* __restrict__ bias1,
    float* __restrict__ t) {
  __shared__ __align__(16) float lx[3][16][PXT];   // 12 KB triple buffer

  const int tid = threadIdx.x;
  const int px  = tid & 63;
  const int wv  = __builtin_amdgcn_readfirstlane(tid >> 6);   // 0..3

  const int bid = blockIdx.x;
  const int pc  = bid >> 1;            // pixel chunk 0..783
  const int oh  = bid & 1;             // output half 0..1
  const int px0 = pc * PXT;
  const int b   = px0 / HW;
  const int hw0 = px0 - b * HW;
  const float* xb = x + (size_t)b * CHW + hw0;

  const int rsub = px >> 4;            // 0..3  (row within wave's 4-row slab)
  const int csub = (px & 15) << 2;     // 0,4,..,60 (float col)
  const int lrow = (wv << 2) + rsub;   // lane's row within the 16-row tile

  // prologue: issue tiles 0 and 1 (stay in flight into the loop)
  GLOAD_LDS(xb + (size_t)(lrow) * HW + csub, &lx[0][wv << 2][0], 16);
  GLOAD_LDS(xb + (size_t)(16 + lrow) * HW + csub, &lx[1][wv << 2][0], 16);

  float acc[8];
#pragma unroll
  for (int j = 0; j < 8; ++j) acc[j] = 0.0f;

  for (int k = 0; k < 16; ++k) {
    // wait for tile k only; tile k+1's load stays outstanding
    if (k < 15) {
      asm volatile("s_waitcnt vmcnt(1)" ::: "memory");
    } else {
      asm volatile("s_waitcnt vmcnt(0)" ::: "memory");
    }
    __builtin_amdgcn_s_barrier();      // cross-wave LDS visibility
    __builtin_amdgcn_sched_barrier(0); // no ds_read hoisting above the barrier
    if (k < 14) {                      // issue tile k+2 (overwrites buf read at k-1;
      const int nb = (k + 2) % 3;      //  barrier above proves all waves are past it)
      GLOAD_LDS(xb + (size_t)((k + 2) * 16 + lrow) * HW + csub,
                &lx[nb][wv << 2][0], 16);
    }
    const float* lxk = &lx[k % 3][0][0];
    const float* wr0 = w1f + (k << 10) + (oh << 5) + (wv << 3);
#pragma unroll
    for (int c = 0; c < 16; ++c) {
      const float xv = lxk[(c << 6) + px];
      const float* wr = wr0 + (c << 6);          // wave-uniform -> s_load x2
      const float4 wa = *(const float4*)(wr + 0);
      const float4 wb = *(const float4*)(wr + 4);
      acc[0] = fmaf(xv, wa.x, acc[0]);
      acc[1] = fmaf(xv, wa.y, acc[1]);
      acc[2] = fmaf(xv, wa.z, acc[2]);
      acc[3] = fmaf(xv, wa.w, acc[3]);
      acc[4] = fmaf(xv, wb.x, acc[4]);
      acc[5] = fmaf(xv, wb.y, acc[5]);
      acc[6] = fmaf(xv, wb.z, acc[6]);
      acc[7] = fmaf(xv, wb.w, acc[7]);
    }
  }

#pragma unroll
  for (int j = 0; j < 8; ++j) {
    const int o = (oh << 5) + (wv << 3) + j;
    t[(size_t)o * NPIX + px0 + px] = fmaxf(acc[j] + bias1[o], 0.0f);
  }
}

// ---------------------------------------------------------------------------
// conv2 + involution. Block = 64 px x ONE group-quad, grid 3136.
// bid decode: pc = (bid>>5)*8 + (bid&7), gq = (bid>>3)&3  -> all 4 quads of a
// pc share bid%8 (= conv1 writer's bid%8 = pc%8) AND sit 8 blocks apart in
// dispatch order => t tile is fetched ~once per XCD L2, hot for all quads.
// Involution taps: 4-deep register pipeline (p0..p3), first 4 channels issued
// BEFORE the staging barrier (they complete under the vmcnt drain for free).
// ---------------------------------------------------------------------------
#define LOADCH(dst, ch)                                                   \
  {                                                                       \
    const float* _xp = xcg + (size_t)(ch) * HW;                           \
    _Pragma("unroll")                                                     \
    for (int kk = 0; kk < NKK; ++kk) dst[kk] = _xp[off[kk]];              \
  }
#define CONSUME(src, ch)                                                  \
  {                                                                       \
    float s0 = wk[0] * src[0];                                            \
    float s1 = wk[1] * src[1];                                            \
    float s2 = wk[2] * src[2];                                            \
    s0 = fmaf(wk[3], src[3], s0);                                         \
    s1 = fmaf(wk[4], src[4], s1);                                         \
    s2 = fmaf(wk[5], src[5], s2);                                         \
    s0 = fmaf(wk[6], src[6], s0);                                         \
    s1 = fmaf(wk[7], src[7], s1);                                         \
    s2 = fmaf(wk[8], src[8], s2);                                         \
    ob[(size_t)(ch) * HW] = s0 + s1 + s2;                                 \
  }

__global__ __launch_bounds__(256, 4) void conv2_inv_kernel(
    const float* __restrict__ x,
    const float* __restrict__ t,
    const float* __restrict__ w2,
    const float* __restrict__ b2,
    float* __restrict__ out) {
  __shared__ __align__(16) float lt[MID][PXT];          // 16 KB

  const int tid = threadIdx.x;
  const int px  = tid & 63;
  const int wv  = __builtin_amdgcn_readfirstlane(tid >> 6);   // 0..3

  const int bid = blockIdx.x;
  const int pc  = ((bid >> 5) << 3) + (bid & 7);   // pixel chunk 0..783
  const int gq  = (bid >> 3) & 3;                  // group quad 0..3
  const int g   = (gq << 2) + wv;                  // wave's group (uniform)

  const int px0 = pc * PXT;
  const int b   = px0 / HW;
  const int hw0 = px0 - b * HW;

  const int rsub = px >> 4;
  const int csub = (px & 15) << 2;

  // ---- issue t-tile staging (async) ----
#pragma unroll
  for (int j = 0; j < 4; ++j) {
    const int r0 = (wv << 4) + (j << 2);
    GLOAD_LDS(t + (size_t)(r0 + rsub) * NPIX + px0 + csub, &lt[r0][0], 16);
  }

  // ---- tap geometry (pure VALU, overlaps staging) ----
  const int hw = hw0 + px;
  const int h  = hw / Wn;
  const int w  = hw - h * Wn;

  int off[NKK];
  unsigned vmask = 0;
#pragma unroll
  for (int kk = 0; kk < NKK; ++kk) {
    const int di  = kk / 3 - 1;
    const int dj  = kk % 3 - 1;
    const int h2  = h + di;
    const int w2v = w + dj;
    const bool valid = ((unsigned)h2 < (unsigned)Hn) && ((unsigned)w2v < (unsigned)Wn);
    off[kk] = valid ? (h2 * Wn + w2v) : hw;
    vmask |= (valid ? 1u : 0u) << kk;
  }

  // ---- pre-issue first 4 channels' taps (complete under the barrier drain) ----
  const float* xcg = x + (size_t)b * CHW + (size_t)(g * GSZ) * HW;
  float p0[NKK], p1[NKK], p2[NKK], p3[NKK];
  LOADCH(p0, 0)
  LOADCH(p1, 1)
  LOADCH(p2, 2)
  LOADCH(p3, 3)

  __syncthreads();

  // ---- conv2: per-pixel kernel weights for group g, in registers ----
  float a[NKK];
#pragma unroll
  for (int kk = 0; kk < NKK; ++kk) a[kk] = b2[g * NKK + kk];   // uniform s_load

  const float* wg = w2 + (size_t)g * (NKK * MID);              // uniform base
#pragma unroll 4
  for (int o4 = 0; o4 < MID; o4 += 4) {
    const float t0 = lt[o4 + 0][px];
    const float t1 = lt[o4 + 1][px];
    const float t2 = lt[o4 + 2][px];
    const float t3 = lt[o4 + 3][px];
#pragma unroll
    for (int kk = 0; kk < NKK; ++kk) {
      const float4 w4 = *(const float4*)(wg + (kk << 6) + o4); // scalar pipe
      a[kk] = fmaf(t3, w4.w, fmaf(t2, w4.z, fmaf(t1, w4.y, fmaf(t0, w4.x, a[kk]))));
    }
  }

  float wk[NKK];
#pragma unroll
  for (int kk = 0; kk < NKK; ++kk)
    wk[kk] = ((vmask >> kk) & 1u) ? a[kk] : 0.0f;

  // ---- involution: 4-deep software pipeline over 16 channels ----
  float* ob = out + (size_t)b * CHW + (size_t)(g * GSZ) * HW + hw;

  CONSUME(p0, 0)  LOADCH(p0, 4)
  CONSUME(p1, 1)  LOADCH(p1, 5)
  CONSUME(p2, 2)  LOADCH(p2, 6)
  CONSUME(p3, 3)  LOADCH(p3, 7)
  CONSUME(p0, 4)  LOADCH(p0, 8)
  CONSUME(p1, 5)  LOADCH(p1, 9)
  CONSUME(p2, 6)  LOADCH(p2, 10)
  CONSUME(p3, 7)  LOADCH(p3, 11)
  CONSUME(p0, 8)  LOADCH(p0, 12)
  CONSUME(p1, 9)  LOADCH(p1, 13)
  CONSUME(p2, 10) LOADCH(p2, 14)
  CONSUME(p3, 11) LOADCH(p3, 15)
  CONSUME(p0, 12)
  CONSUME(p1, 13)
  CONSUME(p2, 14)
  CONSUME(p3, 15)
}

// ---------------------------------------------------------------------------
extern "C" void kernel_launch(void* const* d_in, const int* in_sizes, int n_in,
                              void* d_out, int out_size, void* d_ws, size_t ws_size,
                              hipStream_t stream) {
  const float* x     = (const float*)d_in[0];
  const float* w1    = (const float*)d_in[1];
  const float* gamma = (const float*)d_in[2];
  const float* beta  = (const float*)d_in[3];
  const float* mean  = (const float*)d_in[4];
  const float* var   = (const float*)d_in[5];
  const float* w2    = (const float*)d_in[6];
  const float* b2    = (const float*)d_in[7];
  float* out = (float*)d_out;

  // workspace: t (64 x 50176 fp32 = 12.85 MB) | w1f (64 KB) | bias1 (256 B)
  char* ws = (char*)d_ws;
  float* t     = (float*)ws;
  float* w1f   = (float*)(ws + (size_t)MID * NPIX * 4);
  float* bias1 = (float*)(ws + (size_t)MID * NPIX * 4 + (size_t)MID * Cn * 4);

  prep_kernel<<<(MID * Cn + MID + 255) / 256, 256, 0, stream>>>(
      w1, gamma, beta, mean, var, w1f, bias1);
  conv1_kernel<<<NPIX / PXT * 2, 256, 0, stream>>>(x, w1f, bias1, t);
  conv2_inv_kernel<<<NPIX / PXT * 4, 256, 0, stream>>>(x, t, w2, b2, out);
}